// Round 4
// baseline (151.942 us; speedup 1.0000x reference)
//
#include <hip/hip_runtime.h>

// GraphClusterReshape: out[m, k*64 + f] = nidx[m,k] < 0 ? 0 : features[nidx[m,k], f]
// features: [100000, 64] f32 (25.6 MB), nidx: [50000, 32] i32, out: [50000, 2048] f32 (409.6 MB).
//
// R3 post-mortem: nt stores alone regressed (123->130 us). The 410 MB write
// stream turns over L3 (256 MB) every call and L2 (4 MB/XCD) every few us, so
// the 12.8x gather reuse (spread uniformly in time) mostly misses to HBM:
// 410 + ~330 + 6 MB at ~6 TB/s = 123 us. Cache hints can't fix temporal
// spread; restructure instead.
//
// R4: feature-blocked multi-pass. 13 blocks x 8192 feature rows (2 MB, fits
// per-XCD L2). Each WG holds its 25 rows' nidx in LDS and, per pass p, only
// performs gathers with idx in block p (zero-fills invalid slots in pass 0).
// Same-block reads compact into a short window -> L2/L3-resident across the
// full reuse. Writes: 256 B per 16-lane group, nt (never re-read, protect L2).
// Expected HBM: 410 write + ~30-60 read -> ~85-100 us.

typedef float f32x4 __attribute__((ext_vector_type(4)));

constexpr int M_ROWS = 50000;
constexpr int K_NEIGH = 32;
constexpr int F4 = 16;                       // float4 per feature row (64 f32)
constexpr int ROWS_PER_WG = 25;
constexpr int SLOTS = ROWS_PER_WG * K_NEIGH; // 800
constexpr int BLOCK_SHIFT = 13;              // 8192 feature rows per pass block
constexpr int NPASS = 13;                    // ceil(100000 / 8192)
constexpr int SENTINEL = 0x7f000000;         // row beyond M: never matches, not <0

__global__ __launch_bounds__(256, 8)
void gcr_blocked_kernel(const f32x4* __restrict__ feat4,
                        const int* __restrict__ nidx,
                        f32x4* __restrict__ out4) {
    __shared__ int s_idx[SLOTS];
    const int row0 = blockIdx.x * ROWS_PER_WG;
    const int tid = threadIdx.x;

    // Stage this WG's nidx chunk in LDS (3.2 KB).
    for (int s = tid; s < SLOTS; s += 256) {
        const int m = row0 + (s >> 5);
        s_idx[s] = (m < M_ROWS) ? nidx[m * K_NEIGH + (s & 31)] : SENTINEL;
    }
    __syncthreads();

    const int g = tid >> 4;   // 16-lane group id, 0..15
    const int e = tid & 15;   // float4 lane within feature row

    for (int p = 0; p < NPASS; ++p) {
        for (int s = g; s < SLOTS; s += 16) {
            const int idx = s_idx[s];
            const bool zero  = (idx < 0) & (p == 0);
            const bool match = (idx >= 0) & ((idx >> BLOCK_SHIFT) == p);
            if (zero | match) {
                f32x4 v = match ? feat4[(long long)idx * F4 + e] : (f32x4)(0.f);
                const long long m = row0 + (s >> 5);
                const long long o = m * (long long)(K_NEIGH * F4)
                                  + (long long)(s & 31) * F4 + e;
                __builtin_nontemporal_store(v, &out4[o]);
            }
        }
        __syncthreads();   // keep the WG's groups pass-coherent
    }
}

extern "C" void kernel_launch(void* const* d_in, const int* in_sizes, int n_in,
                              void* d_out, int out_size, void* d_ws, size_t ws_size,
                              hipStream_t stream) {
    const f32x4* feat4 = (const f32x4*)d_in[0];   // features [100000, 64] f32
    const int*   nidx  = (const int*)d_in[1];     // nidx [50000, 32] i32
    f32x4*       out4  = (f32x4*)d_out;           // [50000, 2048] f32

    const int grid = (M_ROWS + ROWS_PER_WG - 1) / ROWS_PER_WG;  // 2000 WGs

    gcr_blocked_kernel<<<grid, 256, 0, stream>>>(feat4, nidx, out4);
}